// Round 4
// baseline (71.513 us; speedup 1.0000x reference)
//
#include <hip/hip_runtime.h>
#include <math.h>

// PyramidROIAlign: B=2, N=1000, C=256, 7x7 pool, levels P2..P5 (256/128/64/32).
// Phase 1: one thread per output pixel resolves EVERYTHING (level, 4 absolute
//          corner offsets, lx, ly) into a 32B record.
// Phase 2: pure gather+lerp, 16 channels/thread -> 16 loads in flight.

#define POOLN 7
#define CCH 256

typedef float f32x4 __attribute__((ext_vector_type(4)));
typedef int   i32x4 __attribute__((ext_vector_type(4)));

struct __align__(16) PixRec {
    int   tl, tr, bl, br;   // element offsets into the selected level map
    float lx, ly;
    int   li, pad;
};

// ---------------- phase 1: per-pixel record ----------------
__global__ __launch_bounds__(256) void roi_prep_kernel(
    const float* __restrict__ boxes,
    const float* __restrict__ meta,
    PixRec* __restrict__ recs,
    int n_boxes, int boxes_per_batch)
{
    int t = blockIdx.x * blockDim.x + threadIdx.x;
    int total = n_boxes * 49;
    if (t >= total) return;

    int box = t / 49;
    int p   = t - box * 49;
    int py  = (p * 37) >> 8;            // p/7 for p in [0,49)
    int px  = p - py * 7;

    float by1 = boxes[4 * box + 0];
    float bx1 = boxes[4 * box + 1];
    float by2 = boxes[4 * box + 2];
    float bx2 = boxes[4 * box + 3];
    float h = by2 - by1, w = bx2 - bx1;

    // level: clip(4 + round_half_even(log2(sqrt(hw)/(224/sqrt(area)))), 2, 5)
    float area  = meta[4] * meta[5];
    float scale = 224.0f / sqrtf(area);
    float rl    = log2f(sqrtf(h * w) / scale);
    int lvl = 4 + (int)rintf(rl);
    lvl = lvl < 2 ? 2 : (lvl > 5 ? 5 : lvl);
    int li = lvl - 2;
    int H  = 256 >> li;
    float hm1 = (float)(H - 1);
    int b = box / boxes_per_batch;

    // y axis (reference arithmetic order)
    float gy  = (float)py / 6.0f;
    float ys  = (by1 + h * gy) * hm1;
    float fy0 = fminf(fmaxf(floorf(ys), 0.0f), hm1);
    int y0  = (int)fy0;
    int y1i = min(y0 + 1, H - 1);

    // x axis
    float gx  = (float)px / 6.0f;
    float xs  = (bx1 + w * gx) * hm1;
    float fx0 = fminf(fmaxf(floorf(xs), 0.0f), hm1);
    int x0  = (int)fx0;
    int x1i = min(x0 + 1, H - 1);

    int row0 = (b * H + y0)  * H;
    int row1 = (b * H + y1i) * H;

    PixRec r;
    r.tl = (row0 + x0)  * CCH;
    r.tr = (row0 + x1i) * CCH;
    r.bl = (row1 + x0)  * CCH;
    r.br = (row1 + x1i) * CCH;
    r.lx = xs - fx0;
    r.ly = ys - fy0;
    r.li = li;
    r.pad = 0;
    recs[t] = r;
}

// ---------------- phase 2: gather + bilinear lerp ----------------
__device__ __forceinline__ f32x4 bilerp4(f32x4 tl, f32x4 tr, f32x4 bl, f32x4 br,
                                         float lx, float ly)
{
    f32x4 r;
    float top, bot;
    top = tl.x + (tr.x - tl.x) * lx; bot = bl.x + (br.x - bl.x) * lx; r.x = top + (bot - top) * ly;
    top = tl.y + (tr.y - tl.y) * lx; bot = bl.y + (br.y - bl.y) * lx; r.y = top + (bot - top) * ly;
    top = tl.z + (tr.z - tl.z) * lx; bot = bl.z + (br.z - bl.z) * lx; r.z = top + (bot - top) * ly;
    top = tl.w + (tr.w - tl.w) * lx; bot = bl.w + (br.w - bl.w) * lx; r.w = top + (bot - top) * ly;
    return r;
}

__global__ __launch_bounds__(256) void roi_gather_kernel(
    const PixRec* __restrict__ recs,
    const float* __restrict__ f2,
    const float* __restrict__ f3,
    const float* __restrict__ f4,
    const float* __restrict__ f5,
    float* __restrict__ out,
    int q, int r, long total)
{
    // bijective XCD-chunked swizzle (nwg = 8q + r)
    int bid    = blockIdx.x;
    int xcd    = bid & 7;
    int within = bid >> 3;
    int wg = (xcd < r ? xcd * (q + 1) : r * (q + 1) + (xcd - r) * q) + within;

    long wid = (long)wg * 256 + threadIdx.x;
    if (wid >= total) return;

    int  c16 = (int)(wid & 15);        // which 16-channel slab
    long t   = wid >> 4;               // (box,pixel)

    PixRec rec = recs[t];              // 32B, broadcast within 16-lane groups
    const float* f = (rec.li == 0) ? f2 : (rec.li == 1) ? f3 : (rec.li == 2) ? f4 : f5;
    float lx = rec.lx, ly = rec.ly;

    int co = c16 * 16;
    const f32x4* ptl = (const f32x4*)(f + rec.tl + co);
    const f32x4* ptr2= (const f32x4*)(f + rec.tr + co);
    const f32x4* pbl = (const f32x4*)(f + rec.bl + co);
    const f32x4* pbr = (const f32x4*)(f + rec.br + co);

    // 16 independent loads in flight
    f32x4 tl0 = ptl[0], tl1 = ptl[1], tl2 = ptl[2], tl3 = ptl[3];
    f32x4 tr0 = ptr2[0], tr1 = ptr2[1], tr2 = ptr2[2], tr3 = ptr2[3];
    f32x4 bl0 = pbl[0], bl1 = pbl[1], bl2 = pbl[2], bl3 = pbl[3];
    f32x4 br0 = pbr[0], br1 = pbr[1], br2 = pbr[2], br3 = pbr[3];

    f32x4 r0 = bilerp4(tl0, tr0, bl0, br0, lx, ly);
    f32x4 r1 = bilerp4(tl1, tr1, bl1, br1, lx, ly);
    f32x4 r2 = bilerp4(tl2, tr2, bl2, br2, lx, ly);
    f32x4 r3 = bilerp4(tl3, tr3, bl3, br3, lx, ly);

    f32x4* po = (f32x4*)(out + t * CCH + co);
    po[0] = r0; po[1] = r1; po[2] = r2; po[3] = r3;
}

// ---------------- fallback: single kernel (round-1) ----------------
__global__ __launch_bounds__(256) void roi_align_kernel(
    const float* __restrict__ boxes,
    const float* __restrict__ meta,
    const float* __restrict__ f2,
    const float* __restrict__ f3,
    const float* __restrict__ f4,
    const float* __restrict__ f5,
    float* __restrict__ out,
    int boxes_per_batch,
    long total4)
{
    long idx = (long)blockIdx.x * blockDim.x + threadIdx.x;
    if (idx >= total4) return;

    int c4  = (int)(idx & 63);
    long t  = idx >> 6;
    int p   = (int)(t % 49);
    int box = (int)(t / 49);
    int py = p / 7, px = p % 7;

    float by1 = boxes[4 * box + 0];
    float bx1 = boxes[4 * box + 1];
    float by2 = boxes[4 * box + 2];
    float bx2 = boxes[4 * box + 3];

    float h = by2 - by1, w = bx2 - bx1;
    float area  = meta[4] * meta[5];
    float scale = 224.0f / sqrtf(area);
    float rl    = log2f(sqrtf(h * w) / scale);
    int lvl = 4 + (int)rintf(rl);
    lvl = lvl < 2 ? 2 : (lvl > 5 ? 5 : lvl);
    int li = lvl - 2;
    const float* f = (li == 0) ? f2 : (li == 1) ? f3 : (li == 2) ? f4 : f5;
    int H = 256 >> li;

    int b = box / boxes_per_batch;

    float gy = (float)py / 6.0f;
    float gx = (float)px / 6.0f;
    float ys = (by1 + (by2 - by1) * gy) * (float)(H - 1);
    float xs = (bx1 + (bx2 - bx1) * gx) * (float)(H - 1);

    float fy0 = fminf(fmaxf(floorf(ys), 0.0f), (float)(H - 1));
    float fx0 = fminf(fmaxf(floorf(xs), 0.0f), (float)(H - 1));
    int y0 = (int)fy0, x0 = (int)fx0;
    int y1i = min(y0 + 1, H - 1);
    int x1i = min(x0 + 1, H - 1);
    float ly = ys - fy0;
    float lx = xs - fx0;

    size_t row0 = ((size_t)b * H + y0)  * H;
    size_t row1 = ((size_t)b * H + y1i) * H;
    const f32x4* tl = (const f32x4*)(f + (row0 + x0)  * CCH) + c4;
    const f32x4* tr = (const f32x4*)(f + (row0 + x1i) * CCH) + c4;
    const f32x4* bl = (const f32x4*)(f + (row1 + x0)  * CCH) + c4;
    const f32x4* br = (const f32x4*)(f + (row1 + x1i) * CCH) + c4;

    f32x4 rr = bilerp4(*tl, *tr, *bl, *br, lx, ly);
    ((f32x4*)out)[idx] = rr;
}

extern "C" void kernel_launch(void* const* d_in, const int* in_sizes, int n_in,
                              void* d_out, int out_size, void* d_ws, size_t ws_size,
                              hipStream_t stream) {
    const float* boxes = (const float*)d_in[0];
    const float* meta  = (const float*)d_in[1];
    const float* f2    = (const float*)d_in[2];
    const float* f3    = (const float*)d_in[3];
    const float* f4    = (const float*)d_in[4];
    const float* f5    = (const float*)d_in[5];
    float* out         = (float*)d_out;

    int n_boxes = in_sizes[0] / 4;                       // B*N = 2000
    int B       = in_sizes[2] / (256 * 256 * 256);       // batch from feat_p2
    int boxes_per_batch = n_boxes / B;                   // N

    int    n_pix = n_boxes * 49;
    size_t need  = (size_t)n_pix * sizeof(PixRec);

    if (d_ws != nullptr && ws_size >= need) {
        PixRec* recs = (PixRec*)d_ws;

        roi_prep_kernel<<<(n_pix + 255) / 256, 256, 0, stream>>>(
            boxes, meta, recs, n_boxes, boxes_per_batch);

        long total = (long)n_pix * 16;                   // threads (16 ch each)
        int  nwg   = (int)((total + 255) / 256);
        int  q = nwg >> 3, r = nwg & 7;
        roi_gather_kernel<<<nwg, 256, 0, stream>>>(
            recs, f2, f3, f4, f5, out, q, r, total);
    } else {
        long total4 = (long)n_boxes * 49 * 64;
        int  blocks = (int)((total4 + 255) / 256);
        roi_align_kernel<<<blocks, 256, 0, stream>>>(
            boxes, meta, f2, f3, f4, f5, out, boxes_per_batch, total4);
    }
}

// Round 5
// 46.152 us; speedup vs baseline: 1.5495x; 1.5495x over previous
//
#include <hip/hip_runtime.h>
#include <math.h>

// PyramidROIAlign: B=2, N=1000, C=256, 7x7 pool, levels P2..P5 (256/128/64/32).
// Phase 1: one thread per output pixel resolves level + 4 absolute corner
//          offsets + lx/ly into a 32B record.
// Phase 2: gather+lerp. 16 channels/thread via INTERLEAVED float4 slots
//          (thread c16 owns slots c16, c16+16, c16+32, c16+48) so every load
//          instruction is a contiguous 256B run per 16-lane group, while
//          keeping 16 independent loads in flight per thread.

#define POOLN 7
#define CCH 256

typedef float f32x4 __attribute__((ext_vector_type(4)));

struct __align__(16) PixRec {
    int   tl, tr, bl, br;   // element offsets into the selected level map
    float lx, ly;
    int   li, pad;
};

// ---------------- phase 1: per-pixel record ----------------
__global__ __launch_bounds__(256) void roi_prep_kernel(
    const float* __restrict__ boxes,
    const float* __restrict__ meta,
    PixRec* __restrict__ recs,
    int n_boxes, int boxes_per_batch)
{
    int t = blockIdx.x * blockDim.x + threadIdx.x;
    int total = n_boxes * 49;
    if (t >= total) return;

    int box = t / 49;
    int p   = t - box * 49;
    int py  = (p * 37) >> 8;            // p/7 for p in [0,49)
    int px  = p - py * 7;

    float by1 = boxes[4 * box + 0];
    float bx1 = boxes[4 * box + 1];
    float by2 = boxes[4 * box + 2];
    float bx2 = boxes[4 * box + 3];
    float h = by2 - by1, w = bx2 - bx1;

    // level: clip(4 + round_half_even(log2(sqrt(hw)/(224/sqrt(area)))), 2, 5)
    float area  = meta[4] * meta[5];
    float scale = 224.0f / sqrtf(area);
    float rl    = log2f(sqrtf(h * w) / scale);
    int lvl = 4 + (int)rintf(rl);
    lvl = lvl < 2 ? 2 : (lvl > 5 ? 5 : lvl);
    int li = lvl - 2;
    int H  = 256 >> li;
    float hm1 = (float)(H - 1);
    int b = box / boxes_per_batch;

    // y axis (reference arithmetic order)
    float gy  = (float)py / 6.0f;
    float ys  = (by1 + h * gy) * hm1;
    float fy0 = fminf(fmaxf(floorf(ys), 0.0f), hm1);
    int y0  = (int)fy0;
    int y1i = min(y0 + 1, H - 1);

    // x axis
    float gx  = (float)px / 6.0f;
    float xs  = (bx1 + w * gx) * hm1;
    float fx0 = fminf(fmaxf(floorf(xs), 0.0f), hm1);
    int x0  = (int)fx0;
    int x1i = min(x0 + 1, H - 1);

    int row0 = (b * H + y0)  * H;
    int row1 = (b * H + y1i) * H;

    PixRec r;
    r.tl = (row0 + x0)  * CCH;
    r.tr = (row0 + x1i) * CCH;
    r.bl = (row1 + x0)  * CCH;
    r.br = (row1 + x1i) * CCH;
    r.lx = xs - fx0;
    r.ly = ys - fy0;
    r.li = li;
    r.pad = 0;
    recs[t] = r;
}

// ---------------- phase 2: gather + bilinear lerp ----------------
__device__ __forceinline__ f32x4 bilerp4(f32x4 tl, f32x4 tr, f32x4 bl, f32x4 br,
                                         float lx, float ly)
{
    f32x4 r;
    float top, bot;
    top = tl.x + (tr.x - tl.x) * lx; bot = bl.x + (br.x - bl.x) * lx; r.x = top + (bot - top) * ly;
    top = tl.y + (tr.y - tl.y) * lx; bot = bl.y + (br.y - bl.y) * lx; r.y = top + (bot - top) * ly;
    top = tl.z + (tr.z - tl.z) * lx; bot = bl.z + (br.z - bl.z) * lx; r.z = top + (bot - top) * ly;
    top = tl.w + (tr.w - tl.w) * lx; bot = bl.w + (br.w - bl.w) * lx; r.w = top + (bot - top) * ly;
    return r;
}

__global__ __launch_bounds__(256) void roi_gather_kernel(
    const PixRec* __restrict__ recs,
    const float* __restrict__ f2,
    const float* __restrict__ f3,
    const float* __restrict__ f4,
    const float* __restrict__ f5,
    float* __restrict__ out,
    int q, int r, long total)
{
    // bijective XCD-chunked swizzle (nwg = 8q + r)
    int bid    = blockIdx.x;
    int xcd    = bid & 7;
    int within = bid >> 3;
    int wg = (xcd < r ? xcd * (q + 1) : r * (q + 1) + (xcd - r) * q) + within;

    long wid = (long)wg * 256 + threadIdx.x;
    if (wid >= total) return;

    int  c16 = (int)(wid & 15);        // which float4 slot within each 16-slot group
    long t   = wid >> 4;               // (box,pixel)

    PixRec rec = recs[t];              // 32B, broadcast within 16-lane groups
    const float* f = (rec.li == 0) ? f2 : (rec.li == 1) ? f3 : (rec.li == 2) ? f4 : f5;
    float lx = rec.lx, ly = rec.ly;

    // interleaved slots: lane c16 handles float4 indices c16 + {0,16,32,48}
    const f32x4* ptl = (const f32x4*)(f + rec.tl) + c16;
    const f32x4* ptr2= (const f32x4*)(f + rec.tr) + c16;
    const f32x4* pbl = (const f32x4*)(f + rec.bl) + c16;
    const f32x4* pbr = (const f32x4*)(f + rec.br) + c16;

    // 16 independent, per-instruction-contiguous loads in flight
    f32x4 tl0 = ptl[0],  tr0 = ptr2[0],  bl0 = pbl[0],  br0 = pbr[0];
    f32x4 tl1 = ptl[16], tr1 = ptr2[16], bl1 = pbl[16], br1 = pbr[16];
    f32x4 tl2 = ptl[32], tr2 = ptr2[32], bl2 = pbl[32], br2 = pbr[32];
    f32x4 tl3 = ptl[48], tr3 = ptr2[48], bl3 = pbl[48], br3 = pbr[48];

    f32x4 r0 = bilerp4(tl0, tr0, bl0, br0, lx, ly);
    f32x4 r1 = bilerp4(tl1, tr1, bl1, br1, lx, ly);
    f32x4 r2 = bilerp4(tl2, tr2, bl2, br2, lx, ly);
    f32x4 r3 = bilerp4(tl3, tr3, bl3, br3, lx, ly);

    f32x4* po = (f32x4*)(out + t * CCH) + c16;
    po[0]  = r0;
    po[16] = r1;
    po[32] = r2;
    po[48] = r3;
}

// ---------------- fallback: single kernel (round-1) ----------------
__global__ __launch_bounds__(256) void roi_align_kernel(
    const float* __restrict__ boxes,
    const float* __restrict__ meta,
    const float* __restrict__ f2,
    const float* __restrict__ f3,
    const float* __restrict__ f4,
    const float* __restrict__ f5,
    float* __restrict__ out,
    int boxes_per_batch,
    long total4)
{
    long idx = (long)blockIdx.x * blockDim.x + threadIdx.x;
    if (idx >= total4) return;

    int c4  = (int)(idx & 63);
    long t  = idx >> 6;
    int p   = (int)(t % 49);
    int box = (int)(t / 49);
    int py = p / 7, px = p % 7;

    float by1 = boxes[4 * box + 0];
    float bx1 = boxes[4 * box + 1];
    float by2 = boxes[4 * box + 2];
    float bx2 = boxes[4 * box + 3];

    float h = by2 - by1, w = bx2 - bx1;
    float area  = meta[4] * meta[5];
    float scale = 224.0f / sqrtf(area);
    float rl    = log2f(sqrtf(h * w) / scale);
    int lvl = 4 + (int)rintf(rl);
    lvl = lvl < 2 ? 2 : (lvl > 5 ? 5 : lvl);
    int li = lvl - 2;
    const float* f = (li == 0) ? f2 : (li == 1) ? f3 : (li == 2) ? f4 : f5;
    int H = 256 >> li;

    int b = box / boxes_per_batch;

    float gy = (float)py / 6.0f;
    float gx = (float)px / 6.0f;
    float ys = (by1 + (by2 - by1) * gy) * (float)(H - 1);
    float xs = (bx1 + (bx2 - bx1) * gx) * (float)(H - 1);

    float fy0 = fminf(fmaxf(floorf(ys), 0.0f), (float)(H - 1));
    float fx0 = fminf(fmaxf(floorf(xs), 0.0f), (float)(H - 1));
    int y0 = (int)fy0, x0 = (int)fx0;
    int y1i = min(y0 + 1, H - 1);
    int x1i = min(x0 + 1, H - 1);
    float ly = ys - fy0;
    float lx = xs - fx0;

    size_t row0 = ((size_t)b * H + y0)  * H;
    size_t row1 = ((size_t)b * H + y1i) * H;
    const f32x4* tl = (const f32x4*)(f + (row0 + x0)  * CCH) + c4;
    const f32x4* tr = (const f32x4*)(f + (row0 + x1i) * CCH) + c4;
    const f32x4* bl = (const f32x4*)(f + (row1 + x0)  * CCH) + c4;
    const f32x4* br = (const f32x4*)(f + (row1 + x1i) * CCH) + c4;

    f32x4 rr = bilerp4(*tl, *tr, *bl, *br, lx, ly);
    ((f32x4*)out)[idx] = rr;
}

extern "C" void kernel_launch(void* const* d_in, const int* in_sizes, int n_in,
                              void* d_out, int out_size, void* d_ws, size_t ws_size,
                              hipStream_t stream) {
    const float* boxes = (const float*)d_in[0];
    const float* meta  = (const float*)d_in[1];
    const float* f2    = (const float*)d_in[2];
    const float* f3    = (const float*)d_in[3];
    const float* f4    = (const float*)d_in[4];
    const float* f5    = (const float*)d_in[5];
    float* out         = (float*)d_out;

    int n_boxes = in_sizes[0] / 4;                       // B*N = 2000
    int B       = in_sizes[2] / (256 * 256 * 256);       // batch from feat_p2
    int boxes_per_batch = n_boxes / B;                   // N

    int    n_pix = n_boxes * 49;
    size_t need  = (size_t)n_pix * sizeof(PixRec);

    if (d_ws != nullptr && ws_size >= need) {
        PixRec* recs = (PixRec*)d_ws;

        roi_prep_kernel<<<(n_pix + 255) / 256, 256, 0, stream>>>(
            boxes, meta, recs, n_boxes, boxes_per_batch);

        long total = (long)n_pix * 16;                   // threads (16 ch each)
        int  nwg   = (int)((total + 255) / 256);
        int  q = nwg >> 3, r = nwg & 7;
        roi_gather_kernel<<<nwg, 256, 0, stream>>>(
            recs, f2, f3, f4, f5, out, q, r, total);
    } else {
        long total4 = (long)n_boxes * 49 * 64;
        int  blocks = (int)((total4 + 255) / 256);
        roi_align_kernel<<<blocks, 256, 0, stream>>>(
            boxes, meta, f2, f3, f4, f5, out, boxes_per_batch, total4);
    }
}

// Round 6
// 42.848 us; speedup vs baseline: 1.6690x; 1.0771x over previous
//
#include <hip/hip_runtime.h>
#include <math.h>

// PyramidROIAlign: B=2, N=1000, C=256, 7x7 pool, levels P2..P5 (256/128/64/32).
// Phase 1: one thread per output pixel resolves level + 4 absolute corner
//          offsets + lx/ly into one 32B PixRec (single dependent hop).
// Phase 2: round-3's proven layout: 8 floats/thread, c4 in [0,32),
//          slots co=c4*4 and co+128 (contiguous 512B per 32-lane half-wave),
//          nontemporal stores, XCD-chunked swizzle.

#define POOLN 7
#define CCH 256

typedef float f32x4 __attribute__((ext_vector_type(4)));

struct __align__(16) PixRec {
    int   tl, tr, bl, br;   // element offsets into the selected level map
    float lx, ly;
    int   li, pad;
};

// ---------------- phase 1: per-pixel record ----------------
__global__ __launch_bounds__(256) void roi_prep_kernel(
    const float* __restrict__ boxes,
    const float* __restrict__ meta,
    PixRec* __restrict__ recs,
    int n_boxes, int boxes_per_batch)
{
    int t = blockIdx.x * blockDim.x + threadIdx.x;
    int total = n_boxes * 49;
    if (t >= total) return;

    int box = t / 49;
    int p   = t - box * 49;
    int py  = (p * 37) >> 8;            // p/7 for p in [0,49)
    int px  = p - py * 7;

    float by1 = boxes[4 * box + 0];
    float bx1 = boxes[4 * box + 1];
    float by2 = boxes[4 * box + 2];
    float bx2 = boxes[4 * box + 3];
    float h = by2 - by1, w = bx2 - bx1;

    // level: clip(4 + round_half_even(log2(sqrt(hw)/(224/sqrt(area)))), 2, 5)
    float area  = meta[4] * meta[5];
    float scale = 224.0f / sqrtf(area);
    float rl    = log2f(sqrtf(h * w) / scale);
    int lvl = 4 + (int)rintf(rl);
    lvl = lvl < 2 ? 2 : (lvl > 5 ? 5 : lvl);
    int li = lvl - 2;
    int H  = 256 >> li;
    float hm1 = (float)(H - 1);
    int b = box / boxes_per_batch;

    // y axis (reference arithmetic order)
    float gy  = (float)py / 6.0f;
    float ys  = (by1 + h * gy) * hm1;
    float fy0 = fminf(fmaxf(floorf(ys), 0.0f), hm1);
    int y0  = (int)fy0;
    int y1i = min(y0 + 1, H - 1);

    // x axis
    float gx  = (float)px / 6.0f;
    float xs  = (bx1 + w * gx) * hm1;
    float fx0 = fminf(fmaxf(floorf(xs), 0.0f), hm1);
    int x0  = (int)fx0;
    int x1i = min(x0 + 1, H - 1);

    int row0 = (b * H + y0)  * H;
    int row1 = (b * H + y1i) * H;

    PixRec r;
    r.tl = (row0 + x0)  * CCH;
    r.tr = (row0 + x1i) * CCH;
    r.bl = (row1 + x0)  * CCH;
    r.br = (row1 + x1i) * CCH;
    r.lx = xs - fx0;
    r.ly = ys - fy0;
    r.li = li;
    r.pad = 0;
    recs[t] = r;
}

// ---------------- phase 2: gather + bilinear lerp ----------------
__device__ __forceinline__ f32x4 bilerp4(f32x4 tl, f32x4 tr, f32x4 bl, f32x4 br,
                                         float lx, float ly)
{
    f32x4 r;
    float top, bot;
    top = tl.x + (tr.x - tl.x) * lx; bot = bl.x + (br.x - bl.x) * lx; r.x = top + (bot - top) * ly;
    top = tl.y + (tr.y - tl.y) * lx; bot = bl.y + (br.y - bl.y) * lx; r.y = top + (bot - top) * ly;
    top = tl.z + (tr.z - tl.z) * lx; bot = bl.z + (br.z - bl.z) * lx; r.z = top + (bot - top) * ly;
    top = tl.w + (tr.w - tl.w) * lx; bot = bl.w + (br.w - bl.w) * lx; r.w = top + (bot - top) * ly;
    return r;
}

__global__ __launch_bounds__(256) void roi_gather_kernel(
    const PixRec* __restrict__ recs,
    const float* __restrict__ f2,
    const float* __restrict__ f3,
    const float* __restrict__ f4,
    const float* __restrict__ f5,
    float* __restrict__ out,
    int q, int r, long total)
{
    // bijective XCD-chunked swizzle (nwg = 8q + r)
    int bid    = blockIdx.x;
    int xcd    = bid & 7;
    int within = bid >> 3;
    int wg = (xcd < r ? xcd * (q + 1) : r * (q + 1) + (xcd - r) * q) + within;

    long wid = (long)wg * 256 + threadIdx.x;
    if (wid >= total) return;

    int  c4  = (int)(wid & 31);        // slot pair: co = c4*4 and co+128
    long t   = wid >> 5;               // (box,pixel)

    PixRec rec = recs[t];              // ONE 32B broadcast load (single hop)
    const float* f = (rec.li == 0) ? f2 : (rec.li == 1) ? f3 : (rec.li == 2) ? f4 : f5;
    float lx = rec.lx, ly = rec.ly;

    int co = c4 * 4;
    const float* ptl = f + rec.tl + co;
    const float* ptr2= f + rec.tr + co;
    const float* pbl = f + rec.bl + co;
    const float* pbr = f + rec.br + co;

    // 8 independent loads; each instruction = contiguous 512B per 32-lane group
    f32x4 tlA = *(const f32x4*)ptl;
    f32x4 trA = *(const f32x4*)ptr2;
    f32x4 blA = *(const f32x4*)pbl;
    f32x4 brA = *(const f32x4*)pbr;
    f32x4 tlB = *(const f32x4*)(ptl + 128);
    f32x4 trB = *(const f32x4*)(ptr2 + 128);
    f32x4 blB = *(const f32x4*)(pbl + 128);
    f32x4 brB = *(const f32x4*)(pbr + 128);

    f32x4 rA = bilerp4(tlA, trA, blA, brA, lx, ly);
    f32x4 rB = bilerp4(tlB, trB, blB, brB, lx, ly);

    long obase = t * CCH + co;
    __builtin_nontemporal_store(rA, (f32x4*)(out + obase));
    __builtin_nontemporal_store(rB, (f32x4*)(out + obase + 128));
}

// ---------------- fallback: single kernel (round-1) ----------------
__global__ __launch_bounds__(256) void roi_align_kernel(
    const float* __restrict__ boxes,
    const float* __restrict__ meta,
    const float* __restrict__ f2,
    const float* __restrict__ f3,
    const float* __restrict__ f4,
    const float* __restrict__ f5,
    float* __restrict__ out,
    int boxes_per_batch,
    long total4)
{
    long idx = (long)blockIdx.x * blockDim.x + threadIdx.x;
    if (idx >= total4) return;

    int c4  = (int)(idx & 63);
    long t  = idx >> 6;
    int p   = (int)(t % 49);
    int box = (int)(t / 49);
    int py = p / 7, px = p % 7;

    float by1 = boxes[4 * box + 0];
    float bx1 = boxes[4 * box + 1];
    float by2 = boxes[4 * box + 2];
    float bx2 = boxes[4 * box + 3];

    float h = by2 - by1, w = bx2 - bx1;
    float area  = meta[4] * meta[5];
    float scale = 224.0f / sqrtf(area);
    float rl    = log2f(sqrtf(h * w) / scale);
    int lvl = 4 + (int)rintf(rl);
    lvl = lvl < 2 ? 2 : (lvl > 5 ? 5 : lvl);
    int li = lvl - 2;
    const float* f = (li == 0) ? f2 : (li == 1) ? f3 : (li == 2) ? f4 : f5;
    int H = 256 >> li;

    int b = box / boxes_per_batch;

    float gy = (float)py / 6.0f;
    float gx = (float)px / 6.0f;
    float ys = (by1 + (by2 - by1) * gy) * (float)(H - 1);
    float xs = (bx1 + (bx2 - bx1) * gx) * (float)(H - 1);

    float fy0 = fminf(fmaxf(floorf(ys), 0.0f), (float)(H - 1));
    float fx0 = fminf(fmaxf(floorf(xs), 0.0f), (float)(H - 1));
    int y0 = (int)fy0, x0 = (int)fx0;
    int y1i = min(y0 + 1, H - 1);
    int x1i = min(x0 + 1, H - 1);
    float ly = ys - fy0;
    float lx = xs - fx0;

    size_t row0 = ((size_t)b * H + y0)  * H;
    size_t row1 = ((size_t)b * H + y1i) * H;
    const f32x4* tl = (const f32x4*)(f + (row0 + x0)  * CCH) + c4;
    const f32x4* tr = (const f32x4*)(f + (row0 + x1i) * CCH) + c4;
    const f32x4* bl = (const f32x4*)(f + (row1 + x0)  * CCH) + c4;
    const f32x4* br = (const f32x4*)(f + (row1 + x1i) * CCH) + c4;

    f32x4 rr = bilerp4(*tl, *tr, *bl, *br, lx, ly);
    ((f32x4*)out)[idx] = rr;
}

extern "C" void kernel_launch(void* const* d_in, const int* in_sizes, int n_in,
                              void* d_out, int out_size, void* d_ws, size_t ws_size,
                              hipStream_t stream) {
    const float* boxes = (const float*)d_in[0];
    const float* meta  = (const float*)d_in[1];
    const float* f2    = (const float*)d_in[2];
    const float* f3    = (const float*)d_in[3];
    const float* f4    = (const float*)d_in[4];
    const float* f5    = (const float*)d_in[5];
    float* out         = (float*)d_out;

    int n_boxes = in_sizes[0] / 4;                       // B*N = 2000
    int B       = in_sizes[2] / (256 * 256 * 256);       // batch from feat_p2
    int boxes_per_batch = n_boxes / B;                   // N

    int    n_pix = n_boxes * 49;
    size_t need  = (size_t)n_pix * sizeof(PixRec);

    if (d_ws != nullptr && ws_size >= need) {
        PixRec* recs = (PixRec*)d_ws;

        roi_prep_kernel<<<(n_pix + 255) / 256, 256, 0, stream>>>(
            boxes, meta, recs, n_boxes, boxes_per_batch);

        long total = (long)n_pix * 32;                   // threads (8 floats each)
        int  nwg   = (int)((total + 255) / 256);
        int  q = nwg >> 3, r = nwg & 7;
        roi_gather_kernel<<<nwg, 256, 0, stream>>>(
            recs, f2, f3, f4, f5, out, q, r, total);
    } else {
        long total4 = (long)n_boxes * 49 * 64;
        int  blocks = (int)((total4 + 255) / 256);
        roi_align_kernel<<<blocks, 256, 0, stream>>>(
            boxes, meta, f2, f3, f4, f5, out, boxes_per_batch, total4);
    }
}